// Round 6
// baseline (182.627 us; speedup 1.0000x reference)
//
#include <hip/hip_runtime.h>
#include <hip/hip_bf16.h>

typedef __attribute__((ext_vector_type(4))) float f32x4;
typedef __attribute__((ext_vector_type(8))) short bf16x8;

// global -> LDS direct DMA, 16 B/lane. LDS dest = wave-uniform base + lane*16.
#define GLDS16(gp, lp) __builtin_amdgcn_global_load_lds( \
    (__attribute__((address_space(1))) void*)(void*)(gp), \
    (__attribute__((address_space(3))) void*)(lp), 16, 0, 0)

static constexpr int Mtot = 49152;   // 4*24*512 rows (b,h,n)
static constexpr int Otot = 512;
static constexpr int Hh   = 24;
// K order: k = i*6 + f (i: 0..119 = x-ch, 120..127 = t_emb; f: silu, rbf0..4)
// K = 768 = 96 chunks (cc) of 8 k.  GEMM: 8 iters of BK=96 (12 chunks).
// TWO-KERNEL SPLIT: featgen materializes A (49152x768 bf16, 72 MB) once --
// feature VALU paid exactly 1x instead of 4x -- in the GLDS-ready layout
// [m_tile(384)][cc(96)][row(128)]x16B.  gemm_kan is then a pure 2-phase
// GEMM with round-4's proven envelope (128x128, 4 waves, acc[4][4], 48 KB
// chunk-major LDS, 3 blocks/CU).
// RBF constants e^{-4c^2} are folded into Wt, basis = {silu, t*u^-2, t*u^-1,
// t, t*u, t*u^2}, t = exp(-4v^2), u = exp(4v)  (round-5-verified numerics).

__device__ inline unsigned short f2bf(float f) {
    __hip_bfloat16 h = __float2bfloat16(f);
    unsigned short u;
    __builtin_memcpy(&u, &h, 2);
    return u;
}

static constexpr float C1 = 0.36787944117f;   // e^-1
static constexpr float C4 = 0.01831563889f;   // e^-4

// Wt image: [cc(96)][col(512)] x 16B; 16B at (cc,col) = bf16 Ws[k=cc*8+e][col]
// with e^{-4c_g^2} folded: scale(f) = {1, C4, C1, 1, C1, C4}.
__global__ __launch_bounds__(256) void prep_W(
        const float* __restrict__ bw, const float* __restrict__ sw,
        uint4* __restrict__ Wt)
{
    const int tid = blockIdx.x * 256 + threadIdx.x;  // cc*512 + col; 49152 total
    const int col = tid & 511;
    const int cc  = tid >> 9;          // 0..95
    const int k0  = cc * 8;
    const float scale[6] = {1.0f, C4, C1, 1.0f, C1, C4};
    unsigned short s[8];
    #pragma unroll
    for (int e = 0; e < 8; ++e) {
        const int k = k0 + e;
        const int i = k / 6, f = k - i * 6;
        const float v = (f == 0) ? bw[col * 128 + i]
                                 : sw[(col * 128 + i) * 5 + (f - 1)] * scale[f];
        s[e] = f2bf(v);
    }
    uint4 u;
    u.x = s[0] | ((unsigned)s[1] << 16);
    u.y = s[2] | ((unsigned)s[3] << 16);
    u.z = s[4] | ((unsigned)s[5] << 16);
    u.w = s[6] | ((unsigned)s[7] << 16);
    Wt[tid] = u;
}

// featgen: thread = (m_tile, grp, lrow); grp g covers channels 8g..8g+7
// (g=15 -> t_emb).  Writes 6 chunk-16Bs; wave lanes = consecutive rows ->
// every store is a coalesced 1 KB line.  Write-bound (~72 MB).
__global__ __launch_bounds__(256) void featgen(
        const float* __restrict__ x, const int* __restrict__ t_idx,
        const float* __restrict__ temb,
        uint4* __restrict__ Aimg)
{
    const int t    = threadIdx.x;
    const int bid  = blockIdx.x;                // 3072 blocks
    const int lrow = t & 127;
    const int grp  = ((bid & 7) << 1) | (t >> 7);   // 0..15
    const int mt   = bid >> 3;                  // 0..383
    const int row  = mt * 128 + lrow;
    const int ht   = t_idx[(row >> 9) % Hh];

    const float* src = (grp < 15) ? (x + (size_t)row * 120 + grp * 8)
                                  : (temb + ht * 8);
    const float4 a = *(const float4*)src;
    const float4 b = *(const float4*)(src + 4);
    const float v[8] = {a.x, a.y, a.z, a.w, b.x, b.y, b.z, b.w};

    unsigned short s[48];
    #pragma unroll
    for (int c = 0; c < 8; ++c) {
        const float vv = v[c];
        s[c * 6 + 0] = f2bf(vv * __builtin_amdgcn_rcpf(1.0f + __expf(-vv)));
        const float tt = __expf(-4.0f * vv * vv);
        const float uu = __expf(4.0f * vv);
        const float rr = __builtin_amdgcn_rcpf(uu);
        const float tu = tt * uu, tr = tt * rr;
        s[c * 6 + 1] = f2bf(tr * rr);   // c_g = -1   (consts folded in Wt)
        s[c * 6 + 2] = f2bf(tr);        // c_g = -0.5
        s[c * 6 + 3] = f2bf(tt);        // c_g = 0
        s[c * 6 + 4] = f2bf(tu);        // c_g = +0.5
        s[c * 6 + 5] = f2bf(tu * uu);   // c_g = +1
    }

    uint4* dst = Aimg + ((size_t)mt * 96 + grp * 6) * 128 + lrow;
    #pragma unroll
    for (int j = 0; j < 6; ++j) {       // cc = 6*grp + j
        unsigned u[4];
        #pragma unroll
        for (int n = 0; n < 4; ++n)
            u[n] = s[j * 8 + 2 * n] | ((unsigned)s[j * 8 + 2 * n + 1] << 16);
        dst[j * 128] = make_uint4(u[0], u[1], u[2], u[3]);
    }
}

// Pure 2-phase GEMM: round-4 envelope, A staged by GLDS instead of generated.
__global__ __launch_bounds__(256, 3) void gemm_kan(
        const char* __restrict__ Aimg,
        const char* __restrict__ Wt,
        const float* __restrict__ bias,
        float* __restrict__ out)
{
    __shared__ char Alds[12 * 128 * 16];   // 24 KB, [chunk][row]x16B
    __shared__ char Blds[12 * 128 * 16];   // 24 KB, [chunk][col]x16B
    const int t    = threadIdx.x;
    const int wave = t >> 6;
    const int lane = t & 63;
    const int ll   = lane & 15;
    const int q4   = lane >> 4;
    const int wm   = (wave >> 1) * 64;
    const int wn   = (wave & 1) * 64;

    // bijective XCD swizzle: 1536 = 8*192, n fastest -> the 4 n-blocks of an
    // m-panel are co-located on one XCD; its 192 KB A-panel stays L2-hot.
    const int bid = blockIdx.x;
    const int swz = (bid & 7) * 192 + (bid >> 3);
    const int mt  = swz >> 2;
    const int m_base = mt * 128;
    const int n_base = (swz & 3) * 128;

    f32x4 acc[4][4] = {};

    #pragma unroll
    for (int it = 0; it < 8; ++it) {
        // ---- stage A(it): wave stages chunks 3w..3w+2, 2 GLDS each ----
        #pragma unroll
        for (int j = 0; j < 6; ++j) {
            const int c  = wave * 3 + (j >> 1);
            const int rh = (j & 1) * 64;
            const char* srcA = Aimg + (((size_t)mt * 96 + it * 12 + c) * 128
                                       + rh + lane) * 16;
            GLDS16(srcA, Alds + ((c * 128 + rh) << 4));
        }
        // ---- stage B(it): same shape from Wt ----
        #pragma unroll
        for (int j = 0; j < 6; ++j) {
            const int c = wave * 3 + (j >> 1);
            const int g = (j & 1) * 64;
            const char* srcB = Wt + (((size_t)(it * 12 + c) * 512 + n_base + g
                                      + lane) << 4);
            GLDS16(srcB, Blds + ((c * 128 + g) << 4));
        }
        __syncthreads();               // drain GLDS A+B

        #pragma unroll
        for (int kk = 0; kk < 3; ++kk) {
            const int ch = kk * 4 + q4;                  // chunk 0..11
            bf16x8 af[4], bf[4];
            #pragma unroll
            for (int mi = 0; mi < 4; ++mi)
                af[mi] = *(const bf16x8*)(Alds + ((ch * 128 + wm + mi * 16 + ll) << 4));
            #pragma unroll
            for (int ni = 0; ni < 4; ++ni)
                bf[ni] = *(const bf16x8*)(Blds + ((ch * 128 + wn + ni * 16 + ll) << 4));
            #pragma unroll
            for (int mi = 0; mi < 4; ++mi)
                #pragma unroll
                for (int ni = 0; ni < 4; ++ni)
                    acc[mi][ni] = __builtin_amdgcn_mfma_f32_16x16x32_bf16(
                        af[mi], bf[ni], acc[mi][ni], 0, 0, 0);
        }
        __syncthreads();               // LDS consumed before next stage
    }

    // C/D layout: col = lane&15, row = (lane>>4)*4 + reg  [m89-verified]
    const int col0 = n_base + wn + ll;
    const int row0 = m_base + wm + q4 * 4;
    #pragma unroll
    for (int ni = 0; ni < 4; ++ni) {
        const int col = col0 + ni * 16;
        const float bv = bias[col];
        #pragma unroll
        for (int mi = 0; mi < 4; ++mi) {
            #pragma unroll
            for (int r = 0; r < 4; ++r) {
                out[(long)(row0 + mi * 16 + r) * Otot + col] = acc[mi][ni][r] + bv;
            }
        }
    }
}

extern "C" void kernel_launch(void* const* d_in, const int* in_sizes, int n_in,
                              void* d_out, int out_size, void* d_ws, size_t ws_size,
                              hipStream_t stream) {
    const float* x    = (const float*)d_in[0];
    const int*   tidx = (const int*)  d_in[1];
    const float* temb = (const float*)d_in[2];
    const float* bw   = (const float*)d_in[3];
    const float* bb   = (const float*)d_in[4];
    const float* sw   = (const float*)d_in[5];
    float* out = (float*)d_out;

    char* Wt   = (char*)d_ws;                  // 96*512*16 = 768 KiB
    char* Aimg = (char*)d_ws + (1 << 20);      // 384*96*128*16 = 72 MiB

    prep_W<<<49152 / 256, 256, 0, stream>>>(bw, sw, (uint4*)Wt);
    featgen<<<3072, 256, 0, stream>>>(x, tidx, temb, (uint4*)Aimg);
    gemm_kan<<<1536, 256, 0, stream>>>(Aimg, Wt, bb, out);
}

// Round 7
// 172.365 us; speedup vs baseline: 1.0595x; 1.0595x over previous
//
#include <hip/hip_runtime.h>
#include <hip/hip_bf16.h>

typedef __attribute__((ext_vector_type(4))) float f32x4;
typedef __attribute__((ext_vector_type(8))) short bf16x8;

// global -> LDS direct DMA, 16 B/lane. LDS dest = wave-uniform base + lane*16.
#define GLDS16(gp, lp) __builtin_amdgcn_global_load_lds( \
    (__attribute__((address_space(1))) void*)(void*)(gp), \
    (__attribute__((address_space(3))) void*)(lp), 16, 0, 0)

static constexpr int Mtot = 49152;   // 4*24*512 rows (b,h,n)
static constexpr int Otot = 512;
static constexpr int Hh   = 24;
// K order: k = i*6 + f (i: 0..119 = x-ch, 120..127 = t_emb; f: silu, rbf0..4)
// 8 K-iters of BK=96 = 12 chunks of 8 k.  Chunk-major LDS [chunk][row]x16B.
// FUSED + SOFTWARE-PIPELINED: per iter, gen A(it+1) into REGISTERS and stage
// B(it+1) into the second LDS buffer while MFMA(it) runs (separate pipes ->
// within-wave overlap); A regs are committed to LDS after a post-MFMA
// barrier.  LDS = A 24 KB + B 2x24 KB = 72 KB -> 2 blocks/CU.
// RBF constants e^{-4c^2} folded into Wt: basis = {silu, t*u^-2, t*u^-1, t,
// t*u, t*u^2}, t = exp(-4v^2), u = exp(4v)  (round-5/6-verified numerics).

__device__ inline unsigned short f2bf(float f) {
    __hip_bfloat16 h = __float2bfloat16(f);
    unsigned short u;
    __builtin_memcpy(&u, &h, 2);
    return u;
}

static constexpr float C1 = 0.36787944117f;   // e^-1
static constexpr float C4 = 0.01831563889f;   // e^-4

// Wt image: [cc(96)][col(512)] x 16B; 16B at (cc,col) = bf16 Ws[k=cc*8+e][col]
// with e^{-4c_g^2} folded: scale(f) = {1, C4, C1, 1, C1, C4}.
__global__ __launch_bounds__(256) void prep_W(
        const float* __restrict__ bw, const float* __restrict__ sw,
        uint4* __restrict__ Wt)
{
    const int tid = blockIdx.x * 256 + threadIdx.x;  // cc*512 + col; 49152 total
    const int col = tid & 511;
    const int cc  = tid >> 9;          // 0..95
    const int k0  = cc * 8;
    const float scale[6] = {1.0f, C4, C1, 1.0f, C1, C4};
    unsigned short s[8];
    #pragma unroll
    for (int e = 0; e < 8; ++e) {
        const int k = k0 + e;
        const int i = k / 6, f = k - i * 6;
        const float v = (f == 0) ? bw[col * 128 + i]
                                 : sw[(col * 128 + i) * 5 + (f - 1)] * scale[f];
        s[e] = f2bf(v);
    }
    uint4 u;
    u.x = s[0] | ((unsigned)s[1] << 16);
    u.y = s[2] | ((unsigned)s[3] << 16);
    u.z = s[4] | ((unsigned)s[5] << 16);
    u.w = s[6] | ((unsigned)s[7] << 16);
    Wt[tid] = u;
}

__global__ __launch_bounds__(256, 2) void gemm_kan(
        const float* __restrict__ x, const int* __restrict__ t_idx,
        const float* __restrict__ temb,
        const char* __restrict__ Wt,
        const float* __restrict__ bias,
        float* __restrict__ out)
{
    __shared__ char Alds[12 * 128 * 16];       // 24 KB, [chunk][row]x16B
    __shared__ char Blds[2][12 * 128 * 16];    // 2 x 24 KB, [chunk][col]x16B
    const int t    = threadIdx.x;
    const int wave = t >> 6;
    const int lane = t & 63;
    const int ll   = lane & 15;
    const int q4   = lane >> 4;
    const int wm   = (wave >> 1) * 64;
    const int wn   = (wave & 1) * 64;

    // bijective XCD swizzle: 1536 = 8*192, n fastest -> the 4 n-blocks of an
    // m-panel co-located on one XCD (x rows and Wt slice stay L2-hot).
    const int bid = blockIdx.x;
    const int swz = (bid & 7) * 192 + (bid >> 3);
    const int m_base = (swz >> 2) * 128;
    const int n_base = (swz & 3) * 128;

    // ---- A generation mapping: thread = (row, half of 16 channels) ----
    const int row = t >> 1;                     // 0..127
    const int hh  = t & 1;                      // channels hh*8 .. hh*8+7
    const int ht  = t_idx[(m_base >> 9) % Hh];  // uniform per block
    const float* xrow = x + (size_t)(m_base + row) * 120;
    const float* trow = temb + ht * 8;

    auto chanptr = [&](int i0) -> const float* {
        return (i0 < 120) ? (xrow + i0) : (trow + (i0 - 120));
    };

    // B staging: wave stages chunks 3w..3w+2, 2 GLDS each (1 KB)
    auto stageB = [&](int it, int buf) {
        #pragma unroll
        for (int j = 0; j < 6; ++j) {
            const int c = wave * 3 + (j >> 1);
            const int g = (j & 1) * 64;
            const char* src = Wt + (((size_t)(it * 12 + c) * 512 + n_base + g
                                     + lane) << 4);
            GLDS16(src, Blds[buf] + ((c * 128 + g) << 4));
        }
    };

    // 8 channels x 6 features -> 6 packed 16B chunks (registers)
    auto gen = [&](const float4 ca, const float4 cb, uint4* au) {
        const float v[8] = {ca.x, ca.y, ca.z, ca.w, cb.x, cb.y, cb.z, cb.w};
        unsigned short s[48];
        #pragma unroll
        for (int c = 0; c < 8; ++c) {
            const float vv = v[c];
            s[c * 6 + 0] = f2bf(vv * __builtin_amdgcn_rcpf(1.0f + __expf(-vv)));
            const float tt = __expf(-4.0f * vv * vv);
            const float uu = __expf(4.0f * vv);
            const float rr = __builtin_amdgcn_rcpf(uu);
            const float tu = tt * uu, tr = tt * rr;
            s[c * 6 + 1] = f2bf(tr * rr);   // c_g = -1   (consts folded in Wt)
            s[c * 6 + 2] = f2bf(tr);        // c_g = -0.5
            s[c * 6 + 3] = f2bf(tt);        // c_g = 0
            s[c * 6 + 4] = f2bf(tu);        // c_g = +0.5
            s[c * 6 + 5] = f2bf(tu * uu);   // c_g = +1
        }
        #pragma unroll
        for (int j = 0; j < 6; ++j) {
            unsigned u[4];
            #pragma unroll
            for (int n = 0; n < 4; ++n)
                u[n] = s[j * 8 + 2 * n] | ((unsigned)s[j * 8 + 2 * n + 1] << 16);
            au[j] = make_uint4(u[0], u[1], u[2], u[3]);
        }
    };

    auto writeA = [&](const uint4* au) {
        #pragma unroll
        for (int j = 0; j < 6; ++j) {           // chunk ck = 6*hh + j
            const int ck = 6 * hh + j;
            *(uint4*)(Alds + ((ck * 128 + row) << 4)) = au[j];
        }
    };

    f32x4 acc[4][4] = {};

    // ---- prologue: B(0) in flight; A(0) gen+written; x(1) prefetched ----
    stageB(0, 0);
    float4 pa, pb;                              // x for the NEXT gen target
    {
        const float* p0 = chanptr(hh * 8);
        const float4 xa = *(const float4*)p0;
        const float4 xb = *(const float4*)(p0 + 4);
        const float* p1 = chanptr(16 + hh * 8);
        pa = *(const float4*)p1;
        pb = *(const float4*)(p1 + 4);
        uint4 a0[6];
        gen(xa, xb, a0);
        writeA(a0);
    }
    __syncthreads();                            // B(0) drained, A(0) visible

    #pragma unroll
    for (int it = 0; it < 8; ++it) {
        // ---- overlap region: stage B(it+1), gen A(it+1) in regs, MFMA(it) ----
        if (it < 7) stageB(it + 1, (it + 1) & 1);

        const float4 ca = pa, cb = pb;
        if (it < 6) {                           // prefetch x for gen(it+2)
            const float* p = chanptr((it + 2) * 16 + hh * 8);
            pa = *(const float4*)p;
            pb = *(const float4*)(p + 4);
        }
        uint4 au[6];
        if (it < 7) gen(ca, cb, au);            // VALU; independent of MFMA(it)

        const char* B = Blds[it & 1];
        #pragma unroll
        for (int kk = 0; kk < 3; ++kk) {
            const int ch = kk * 4 + q4;                  // chunk 0..11
            bf16x8 af[4], bf[4];
            #pragma unroll
            for (int mi = 0; mi < 4; ++mi)
                af[mi] = *(const bf16x8*)(Alds + ((ch * 128 + wm + mi * 16 + ll) << 4));
            #pragma unroll
            for (int ni = 0; ni < 4; ++ni)
                bf[ni] = *(const bf16x8*)(B + ((ch * 128 + wn + ni * 16 + ll) << 4));
            #pragma unroll
            for (int mi = 0; mi < 4; ++mi)
                #pragma unroll
                for (int ni = 0; ni < 4; ++ni)
                    acc[mi][ni] = __builtin_amdgcn_mfma_f32_16x16x32_bf16(
                        af[mi], bf[ni], acc[mi][ni], 0, 0, 0);
        }

        if (it < 7) {
            __syncthreads();        // all waves done reading A(it); B(it+1) drained
            writeA(au);             // commit A(it+1)
            __syncthreads();        // A(it+1) visible before MFMA(it+1)
        }
    }

    // C/D layout: col = lane&15, row = (lane>>4)*4 + reg  [m89-verified]
    const int col0 = n_base + wn + ll;
    const int row0 = m_base + wm + q4 * 4;
    #pragma unroll
    for (int ni = 0; ni < 4; ++ni) {
        const int col = col0 + ni * 16;
        const float bv = bias[col];
        #pragma unroll
        for (int mi = 0; mi < 4; ++mi) {
            #pragma unroll
            for (int r = 0; r < 4; ++r) {
                out[(long)(row0 + mi * 16 + r) * Otot + col] = acc[mi][ni][r] + bv;
            }
        }
    }
}

extern "C" void kernel_launch(void* const* d_in, const int* in_sizes, int n_in,
                              void* d_out, int out_size, void* d_ws, size_t ws_size,
                              hipStream_t stream) {
    const float* x    = (const float*)d_in[0];
    const int*   tidx = (const int*)  d_in[1];
    const float* temb = (const float*)d_in[2];
    const float* bw   = (const float*)d_in[3];
    const float* bb   = (const float*)d_in[4];
    const float* sw   = (const float*)d_in[5];
    float* out = (float*)d_out;

    char* Wt = (char*)d_ws;   // 96*512*16 = 768 KiB linear chunk-major image

    prep_W<<<49152 / 256, 256, 0, stream>>>(bw, sw, (uint4*)Wt);
    gemm_kan<<<1536, 256, 0, stream>>>(x, tidx, temb, Wt, bb, out);
}

// Round 8
// 164.346 us; speedup vs baseline: 1.1112x; 1.0488x over previous
//
#include <hip/hip_runtime.h>
#include <hip/hip_bf16.h>

typedef __attribute__((ext_vector_type(4))) float f32x4;
typedef __attribute__((ext_vector_type(8))) short bf16x8;

// global -> LDS direct DMA, 16 B/lane. LDS dest = wave-uniform base + lane*16.
#define GLDS16(gp, lp) __builtin_amdgcn_global_load_lds( \
    (__attribute__((address_space(1))) void*)(void*)(gp), \
    (__attribute__((address_space(3))) void*)(lp), 16, 0, 0)

static constexpr int Mtot = 49152;   // 4*24*512 rows (b,h,n)
static constexpr int Otot = 512;
static constexpr int Hh   = 24;
// K order: k = i*6 + f (i: 0..119 = x-ch, 120..127 = t_emb; f: silu, rbf0..4)
// 8 K-iters of BK=96 = 12 chunks of 8 k.  Chunk-major LDS [chunk][row]x16B.
// R4 ENVELOPE (128x128, 4 waves 2x2, acc[4][4], 48 KB LDS, 3 blocks/CU)
// with the iteration REORDERED so gen(it+1) VALU is interleaved into the
// MFMA(it) issue slots (sliced per kk group), held in registers across a
// cheap barrier, then committed to LDS alongside the B(it+1) GLDS stage.
// One heavy barrier per iter instead of two.
// RBF constants e^{-4c^2} folded into Wt: basis = {silu, t*u^-2, t*u^-1, t,
// t*u, t*u^2}, t = exp(-4v^2), u = exp(4v)  (round-4..7-verified numerics).

__device__ inline unsigned short f2bf(float f) {
    __hip_bfloat16 h = __float2bfloat16(f);
    unsigned short u;
    __builtin_memcpy(&u, &h, 2);
    return u;
}

static constexpr float C1 = 0.36787944117f;   // e^-1
static constexpr float C4 = 0.01831563889f;   // e^-4

// Wt image: [cc(96)][col(512)] x 16B; 16B at (cc,col) = bf16 Ws[k=cc*8+e][col]
// with e^{-4c_g^2} folded: scale(f) = {1, C4, C1, 1, C1, C4}.
__global__ __launch_bounds__(256) void prep_W(
        const float* __restrict__ bw, const float* __restrict__ sw,
        uint4* __restrict__ Wt)
{
    const int tid = blockIdx.x * 256 + threadIdx.x;  // cc*512 + col; 49152 total
    const int col = tid & 511;
    const int cc  = tid >> 9;          // 0..95
    const int k0  = cc * 8;
    const float scale[6] = {1.0f, C4, C1, 1.0f, C1, C4};
    unsigned short s[8];
    #pragma unroll
    for (int e = 0; e < 8; ++e) {
        const int k = k0 + e;
        const int i = k / 6, f = k - i * 6;
        const float v = (f == 0) ? bw[col * 128 + i]
                                 : sw[(col * 128 + i) * 5 + (f - 1)] * scale[f];
        s[e] = f2bf(v);
    }
    uint4 u;
    u.x = s[0] | ((unsigned)s[1] << 16);
    u.y = s[2] | ((unsigned)s[3] << 16);
    u.z = s[4] | ((unsigned)s[5] << 16);
    u.w = s[6] | ((unsigned)s[7] << 16);
    Wt[tid] = u;
}

__global__ __launch_bounds__(256, 3) void gemm_kan(
        const float* __restrict__ x, const int* __restrict__ t_idx,
        const float* __restrict__ temb,
        const char* __restrict__ Wt,
        const float* __restrict__ bias,
        float* __restrict__ out)
{
    __shared__ char Alds[12 * 128 * 16];   // 24 KB, [chunk][row]x16B
    __shared__ char Blds[12 * 128 * 16];   // 24 KB, [chunk][col]x16B (single)
    const int t    = threadIdx.x;
    const int wave = t >> 6;
    const int lane = t & 63;
    const int ll   = lane & 15;
    const int q4   = lane >> 4;
    const int wm   = (wave >> 1) * 64;
    const int wn   = (wave & 1) * 64;

    // bijective XCD swizzle: 1536 = 8*192, n fastest -> the 4 n-blocks of an
    // m-panel co-located on one XCD (x rows and Wt slice stay L2-hot).
    const int bid = blockIdx.x;
    const int swz = (bid & 7) * 192 + (bid >> 3);
    const int m_base = (swz >> 2) * 128;
    const int n_base = (swz & 3) * 128;

    // ---- A generation mapping: thread = (row, half of 16 channels) ----
    const int row = t >> 1;                     // 0..127
    const int hh  = t & 1;                      // channels hh*8 .. hh*8+7
    const int ht  = t_idx[(m_base >> 9) % Hh];  // uniform per block
    const float* xrow = x + (size_t)(m_base + row) * 120;
    const float* trow = temb + ht * 8;

    auto chanptr = [&](int i0) -> const float* {
        return (i0 < 120) ? (xrow + i0) : (trow + (i0 - 120));
    };

    // B staging: wave stages chunks 3w..3w+2, 2 GLDS each (1 KB)
    auto stageB = [&](int it) {
        #pragma unroll
        for (int j = 0; j < 6; ++j) {
            const int c = wave * 3 + (j >> 1);
            const int g = (j & 1) * 64;
            const char* src = Wt + (((size_t)(it * 12 + c) * 512 + n_base + g
                                     + lane) << 4);
            GLDS16(src, Blds + ((c * 128 + g) << 4));
        }
    };

    // one channel's 6 features -> s[c*6 .. c*6+5]
    auto genCh = [&](unsigned short* s, int c, float vv) {
        s[c * 6 + 0] = f2bf(vv * __builtin_amdgcn_rcpf(1.0f + __expf(-vv)));
        const float tt = __expf(-4.0f * vv * vv);
        const float uu = __expf(4.0f * vv);
        const float rr = __builtin_amdgcn_rcpf(uu);
        const float tu = tt * uu, tr = tt * rr;
        s[c * 6 + 1] = f2bf(tr * rr);   // c_g = -1   (consts folded in Wt)
        s[c * 6 + 2] = f2bf(tr);        // c_g = -0.5
        s[c * 6 + 3] = f2bf(tt);        // c_g = 0
        s[c * 6 + 4] = f2bf(tu);        // c_g = +0.5
        s[c * 6 + 5] = f2bf(tu * uu);   // c_g = +1
    };

    // pack s[48] and commit to Alds (6 chunk-16B slots, ck = 6*hh + j)
    auto packWriteA = [&](const unsigned short* s) {
        #pragma unroll
        for (int j = 0; j < 6; ++j) {
            unsigned u[4];
            #pragma unroll
            for (int n = 0; n < 4; ++n)
                u[n] = s[j * 8 + 2 * n] | ((unsigned)s[j * 8 + 2 * n + 1] << 16);
            *(uint4*)(Alds + (((6 * hh + j) * 128 + row) << 4)) =
                make_uint4(u[0], u[1], u[2], u[3]);
        }
    };

    f32x4 acc[4][4] = {};
    unsigned short s[48];

    // ---- prologue: B(0) staged, A(0) generated+written, x(1) prefetched ----
    stageB(0);
    {
        const float* p0 = chanptr(hh * 8);
        const float4 ga = *(const float4*)p0;
        const float4 gb = *(const float4*)(p0 + 4);
        const float gv[8] = {ga.x, ga.y, ga.z, ga.w, gb.x, gb.y, gb.z, gb.w};
        #pragma unroll
        for (int c = 0; c < 8; ++c) genCh(s, c, gv[c]);
        packWriteA(s);
    }
    float4 xa, xb;                              // x for gen target it+1
    {
        const float* p1 = chanptr(16 + hh * 8);
        xa = *(const float4*)p1;
        xb = *(const float4*)(p1 + 4);
    }
    __syncthreads();                            // drain B(0) GLDS + A(0) writes

    #pragma unroll
    for (int it = 0; it < 8; ++it) {
        const float4 ca = xa, cb = xb;          // gen(it+1) inputs
        if (it < 6) {                           // prefetch x for gen(it+2)
            const float* p = chanptr((it + 2) * 16 + hh * 8);
            xa = *(const float4*)p;
            xb = *(const float4*)(p + 4);
        }
        const float gv[8] = {ca.x, ca.y, ca.z, ca.w, cb.x, cb.y, cb.z, cb.w};

        // ---- MFMA(it) with gen(it+1) sliced into the issue stream ----
        #pragma unroll
        for (int kk = 0; kk < 3; ++kk) {
            const int ch = kk * 4 + q4;                  // chunk 0..11
            bf16x8 af[4], bf[4];
            #pragma unroll
            for (int mi = 0; mi < 4; ++mi)
                af[mi] = *(const bf16x8*)(Alds + ((ch * 128 + wm + mi * 16 + ll) << 4));
            #pragma unroll
            for (int ni = 0; ni < 4; ++ni)
                bf[ni] = *(const bf16x8*)(Blds + ((ch * 128 + wn + ni * 16 + ll) << 4));
            #pragma unroll
            for (int mi = 0; mi < 4; ++mi)
                #pragma unroll
                for (int ni = 0; ni < 4; ++ni)
                    acc[mi][ni] = __builtin_amdgcn_mfma_f32_16x16x32_bf16(
                        af[mi], bf[ni], acc[mi][ni], 0, 0, 0);
            // gen slice: kk0 -> ch 0..2, kk1 -> ch 3..5, kk2 -> ch 6..7
            if (it < 7) {
                const int c0 = kk * 3;
                const int c1 = (kk == 2) ? 8 : c0 + 3;
                #pragma unroll
                for (int c = c0; c < c1; ++c) genCh(s, c, gv[c]);
            }
        }
        __syncthreads();            // bar1: A(it)/B(it) consumed (cheap drain)

        if (it < 7) {
            stageB(it + 1);         // GLDS issue first (max cover before bar2)
            packWriteA(s);          // pack + 6 ds_write of A(it+1)
            __syncthreads();        // bar2: A visible, B(it+1) drained
        }
    }

    // C/D layout: col = lane&15, row = (lane>>4)*4 + reg  [m89-verified]
    const int col0 = n_base + wn + ll;
    const int row0 = m_base + wm + q4 * 4;
    #pragma unroll
    for (int ni = 0; ni < 4; ++ni) {
        const int col = col0 + ni * 16;
        const float bv = bias[col];
        #pragma unroll
        for (int mi = 0; mi < 4; ++mi) {
            #pragma unroll
            for (int r = 0; r < 4; ++r) {
                out[(long)(row0 + mi * 16 + r) * Otot + col] = acc[mi][ni][r] + bv;
            }
        }
    }
}

extern "C" void kernel_launch(void* const* d_in, const int* in_sizes, int n_in,
                              void* d_out, int out_size, void* d_ws, size_t ws_size,
                              hipStream_t stream) {
    const float* x    = (const float*)d_in[0];
    const int*   tidx = (const int*)  d_in[1];
    const float* temb = (const float*)d_in[2];
    const float* bw   = (const float*)d_in[3];
    const float* bb   = (const float*)d_in[4];
    const float* sw   = (const float*)d_in[5];
    float* out = (float*)d_out;

    char* Wt = (char*)d_ws;   // 96*512*16 = 768 KiB linear chunk-major image

    prep_W<<<49152 / 256, 256, 0, stream>>>(bw, sw, (uint4*)Wt);
    gemm_kan<<<1536, 256, 0, stream>>>(x, tidx, temb, Wt, bb, out);
}